// Round 2
// baseline (692.483 us; speedup 1.0000x reference)
//
#include <hip/hip_runtime.h>
#include <math.h>

// ---------------------------------------------------------------------------
// HybridBinaryClassifier360: conv1(3->6,5x5,s2,p1)+relu+maxpool2s1 ->
// conv2(6->15,3x3,s2,p1)+relu+maxpool2s1 -> fc 55815->120->84->1 ->
// RBF kernel vs 10 supports -> sigmoid -> [p, 1-p]
// B=128. All fp32.
//
// R1: LDS-free register-tiled convs. Each thread owns a strip of 4 pooled
// outputs (all oc for conv1; 5-oc group for conv2), conv values held in
// registers with 2x vertical recompute. Input via clamped global loads *
// precomputed 0/1 masks (no divergent edge branches). Outer loops rolled to
// keep code I$-resident; inner FMA stanzas unrolled.
// ---------------------------------------------------------------------------

#define BATCH 128

// ---------------- Kernel 1: conv1 + relu + maxpool(2,s1) -------------------
// in:  x [128,3,250,250]; w [6,3,5,5]; b [6] -> out: pool1 [128,6,123,123]
// block 256 = 8 pooled rows x 32 strips of 4 cols. grid (16, 1, 128).
__global__ __launch_bounds__(256) void conv1_pool_kernel(
    const float* __restrict__ x, const float* __restrict__ w,
    const float* __restrict__ bias, float* __restrict__ out) {
  const int b = blockIdx.z;
  const int trow = threadIdx.x >> 5;   // 0..7
  const int strip = threadIdx.x & 31;  // 0..31
  const int r = blockIdx.x * 8 + trow; // pooled row, valid < 123
  const int c0 = strip * 4;            // pooled col base, 0..124

  int iwoff[13];
  float cmask[13];
#pragma unroll
  for (int j = 0; j < 13; j++) {
    int iw = 2 * c0 - 1 + j;
    int iwc = iw < 0 ? 0 : (iw > 249 ? 249 : iw);
    iwoff[j] = iwc;
    cmask[j] = (iw >= 0 && iw < 250) ? 1.f : 0.f;
  }

  // acc0 = conv row 2r (rel row r), acc1 = conv row r+1; [conv col dc][oc]
  float acc0[5][6], acc1[5][6];
#pragma unroll
  for (int oc = 0; oc < 6; oc++) {
    float bv = bias[oc];
#pragma unroll
    for (int dc = 0; dc < 5; dc++) { acc0[dc][oc] = bv; acc1[dc][oc] = bv; }
  }

  const int ih_base = 2 * r - 1;
#pragma unroll 1
  for (int ir = 0; ir < 7; ir++) {
    int ih = ih_base + ir;
    int ihc = ih < 0 ? 0 : (ih > 249 ? 249 : ih);
    float rmask = (ih >= 0 && ih < 250) ? 1.f : 0.f;
    float cm[13];
#pragma unroll
    for (int j = 0; j < 13; j++) cm[j] = cmask[j] * rmask;

#pragma unroll 1
    for (int ci = 0; ci < 3; ci++) {
      const float* rowp = x + ((b * 3 + ci) * 250 + ihc) * 250;
      float v[13];
#pragma unroll
      for (int j = 0; j < 13; j++) v[j] = rowp[iwoff[j]] * cm[j];

      if (ir < 5) {  // contributes to conv row r with kh = ir
#pragma unroll
        for (int oc = 0; oc < 6; oc++) {
          const float* wr = w + ((oc * 3 + ci) * 5 + ir) * 5;
          float w0 = wr[0], w1 = wr[1], w2 = wr[2], w3 = wr[3], w4 = wr[4];
#pragma unroll
          for (int dc = 0; dc < 5; dc++) {
            float a = acc0[dc][oc];
            a += w0 * v[2 * dc + 0];
            a += w1 * v[2 * dc + 1];
            a += w2 * v[2 * dc + 2];
            a += w3 * v[2 * dc + 3];
            a += w4 * v[2 * dc + 4];
            acc0[dc][oc] = a;
          }
        }
      }
      if (ir >= 2) {  // contributes to conv row r+1 with kh = ir-2
#pragma unroll
        for (int oc = 0; oc < 6; oc++) {
          const float* wr = w + ((oc * 3 + ci) * 5 + (ir - 2)) * 5;
          float w0 = wr[0], w1 = wr[1], w2 = wr[2], w3 = wr[3], w4 = wr[4];
#pragma unroll
          for (int dc = 0; dc < 5; dc++) {
            float a = acc1[dc][oc];
            a += w0 * v[2 * dc + 0];
            a += w1 * v[2 * dc + 1];
            a += w2 * v[2 * dc + 2];
            a += w3 * v[2 * dc + 3];
            a += w4 * v[2 * dc + 4];
            acc1[dc][oc] = a;
          }
        }
      }
    }
  }

  if (r < 123) {
#pragma unroll
    for (int oc = 0; oc < 6; oc++) {
      float* orow = out + ((size_t)(b * 6 + oc) * 123 + r) * 123;
#pragma unroll
      for (int i = 0; i < 4; i++) {
        int c = c0 + i;
        if (c < 123) {
          float m = fmaxf(fmaxf(acc0[i][oc], acc0[i + 1][oc]),
                          fmaxf(acc1[i][oc], acc1[i + 1][oc]));
          orow[c] = fmaxf(m, 0.f);
        }
      }
    }
  }
}

// ---------------- Kernel 2: conv2 + relu + maxpool(2,s1) -------------------
// in:  pool1 [128,6,123,123]; w [15,6,3,3]; b [15]
// out: act [128, 15*61*61] (NCHW flatten)
// block 256 = 16 pooled rows x 16 strips of 4. grid (4, 3 ocg, 128).
__global__ __launch_bounds__(256) void conv2_pool_kernel(
    const float* __restrict__ in, const float* __restrict__ w,
    const float* __restrict__ bias, float* __restrict__ out) {
  const int b = blockIdx.z;
  const int ocg = blockIdx.y;           // oc = ocg*5 + k
  const int trow = threadIdx.x >> 4;    // 0..15
  const int strip = threadIdx.x & 15;   // 0..15
  const int r = blockIdx.x * 16 + trow; // pooled row, valid < 61
  const int c0 = strip * 4;             // pooled col base, 0..60

  int iwoff[11];
  float cmask[11];
#pragma unroll
  for (int j = 0; j < 11; j++) {
    int iw = 2 * c0 - 1 + j;
    int iwc = iw < 0 ? 0 : (iw > 122 ? 122 : iw);
    iwoff[j] = iwc;
    cmask[j] = (iw >= 0 && iw < 123) ? 1.f : 0.f;
  }

  float acc0[5][5], acc1[5][5];  // [conv col dc][k]
#pragma unroll
  for (int k = 0; k < 5; k++) {
    float bv = bias[ocg * 5 + k];
#pragma unroll
    for (int dc = 0; dc < 5; dc++) { acc0[dc][k] = bv; acc1[dc][k] = bv; }
  }

  const int ih_base = 2 * r - 1;
#pragma unroll 1
  for (int ir = 0; ir < 5; ir++) {
    int ih = ih_base + ir;
    int ihc = ih < 0 ? 0 : (ih > 122 ? 122 : ih);
    float rmask = (ih >= 0 && ih < 123) ? 1.f : 0.f;
    float cm[11];
#pragma unroll
    for (int j = 0; j < 11; j++) cm[j] = cmask[j] * rmask;

#pragma unroll 1
    for (int ci = 0; ci < 6; ci++) {
      const float* rowp = in + ((size_t)(b * 6 + ci) * 123 + ihc) * 123;
      float v[11];
#pragma unroll
      for (int j = 0; j < 11; j++) v[j] = rowp[iwoff[j]] * cm[j];

      if (ir < 3) {  // conv row r, kh = ir
#pragma unroll
        for (int k = 0; k < 5; k++) {
          const float* wr = w + (((ocg * 5 + k) * 6 + ci) * 3 + ir) * 3;
          float w0 = wr[0], w1 = wr[1], w2 = wr[2];
#pragma unroll
          for (int dc = 0; dc < 5; dc++) {
            float a = acc0[dc][k];
            a += w0 * v[2 * dc + 0];
            a += w1 * v[2 * dc + 1];
            a += w2 * v[2 * dc + 2];
            acc0[dc][k] = a;
          }
        }
      }
      if (ir >= 2) {  // conv row r+1, kh = ir-2
#pragma unroll
        for (int k = 0; k < 5; k++) {
          const float* wr = w + (((ocg * 5 + k) * 6 + ci) * 3 + (ir - 2)) * 3;
          float w0 = wr[0], w1 = wr[1], w2 = wr[2];
#pragma unroll
          for (int dc = 0; dc < 5; dc++) {
            float a = acc1[dc][k];
            a += w0 * v[2 * dc + 0];
            a += w1 * v[2 * dc + 1];
            a += w2 * v[2 * dc + 2];
            acc1[dc][k] = a;
          }
        }
      }
    }
  }

  if (r < 61) {
#pragma unroll
    for (int k = 0; k < 5; k++) {
      int oc = ocg * 5 + k;
      float* orow = out + ((size_t)(b * 15 + oc) * 61 + r) * 61;
#pragma unroll
      for (int i = 0; i < 4; i++) {
        int c = c0 + i;
        if (c < 61) {
          float m = fmaxf(fmaxf(acc0[i][k], acc0[i + 1][k]),
                          fmaxf(acc1[i][k], acc1[i + 1][k]));
          orow[c] = fmaxf(m, 0.f);
        }
      }
    }
  }
}

// ---------------- Kernel 3: fc1 split-K GEMM partials ----------------------
#define KTOT 55815
#define NPART 219
__global__ __launch_bounds__(256) void fc1_splitk_kernel(
    const float* __restrict__ act, const float* __restrict__ w,
    float* __restrict__ partial) {
  const int kbase = blockIdx.x * 256;
  const int tid = threadIdx.x;
  const int tx = tid % 16, ty = tid / 16;
  __shared__ float ldsA[8 * 132];
  __shared__ float ldsB[8 * 132];
  float acc[8][8];
#pragma unroll
  for (int i = 0; i < 8; i++)
#pragma unroll
    for (int j = 0; j < 8; j++) acc[i][j] = 0.f;

  for (int s8 = 0; s8 < 32; s8++) {
    int kofs = kbase + s8 * 8;
    __syncthreads();
    for (int i = tid; i < 1024; i += 256) {
      int m = i >> 3, kk = i & 7;
      int k = kofs + kk;
      ldsA[kk * 132 + m] = (k < KTOT) ? act[m * KTOT + k] : 0.f;
    }
    for (int i = tid; i < 960; i += 256) {
      int n = i >> 3, kk = i & 7;
      int k = kofs + kk;
      ldsB[kk * 132 + n] = (k < KTOT) ? w[n * KTOT + k] : 0.f;
    }
    __syncthreads();
#pragma unroll
    for (int kk = 0; kk < 8; kk++) {
      float4 a0 = *(const float4*)&ldsA[kk * 132 + ty * 8];
      float4 a1 = *(const float4*)&ldsA[kk * 132 + ty * 8 + 4];
      float4 b0 = *(const float4*)&ldsB[kk * 132 + tx * 8];
      float4 b1 = *(const float4*)&ldsB[kk * 132 + tx * 8 + 4];
      float av[8] = {a0.x, a0.y, a0.z, a0.w, a1.x, a1.y, a1.z, a1.w};
      float bv[8] = {b0.x, b0.y, b0.z, b0.w, b1.x, b1.y, b1.z, b1.w};
#pragma unroll
      for (int i = 0; i < 8; i++)
#pragma unroll
        for (int j = 0; j < 8; j++) acc[i][j] += av[i] * bv[j];
    }
  }

  float* dst = partial + (size_t)blockIdx.x * 15360;
#pragma unroll
  for (int i = 0; i < 8; i++) {
    int row = ty * 8 + i;
#pragma unroll
    for (int j = 0; j < 8; j++) {
      int col = tx * 8 + j;
      if (col < 120) dst[row * 120 + col] = acc[i][j];
    }
  }
}

// ---------------- Kernel 4: reduce partials + bias + relu ------------------
__global__ __launch_bounds__(256) void fc1_reduce_kernel(
    const float* __restrict__ partial, const float* __restrict__ bias,
    float* __restrict__ h1) {
  int idx = blockIdx.x * 256 + threadIdx.x;
  if (idx >= 15360) return;
  float s = 0.f;
  for (int p = 0; p < NPART; p++) s += partial[(size_t)p * 15360 + idx];
  h1[idx] = fmaxf(s + bias[idx % 120], 0.f);
}

// ---------------- Kernel 5: fc2 + fc3 + RBF + sigmoid ----------------------
__global__ __launch_bounds__(128) void head_kernel(
    const float* __restrict__ h1, const float* __restrict__ fc2_w,
    const float* __restrict__ fc2_b, const float* __restrict__ fc3_w,
    const float* __restrict__ fc3_b, const float* __restrict__ support,
    float* __restrict__ out) {
  int b = blockIdx.x, t = threadIdx.x;
  __shared__ float hrow[120];
  __shared__ float s2[84];
  if (t < 120) hrow[t] = h1[b * 120 + t];
  __syncthreads();
  if (t < 84) {
    float d = fc2_b[t];
    for (int k = 0; k < 120; k++) d += fc2_w[t * 120 + k] * hrow[k];
    s2[t] = fmaxf(d, 0.f);
  }
  __syncthreads();
  if (t == 0) {
    float h = fc3_b[0];
    for (int j = 0; j < 84; j++) h += fc3_w[j] * s2[j];
    float ks = 0.f;
    for (int j = 0; j < 10; j++) {
      float diff = h - support[j];
      ks += expf(-diff * diff);
    }
    ks *= 0.1f;
    float p = 1.f / (1.f + expf(-ks));
    out[b * 2] = p;
    out[b * 2 + 1] = 1.f - p;
  }
}

// ---------------------------------------------------------------------------
extern "C" void kernel_launch(void* const* d_in, const int* in_sizes, int n_in,
                              void* d_out, int out_size, void* d_ws, size_t ws_size,
                              hipStream_t stream) {
  const float* x   = (const float*)d_in[0];
  const float* c1w = (const float*)d_in[1];
  const float* c1b = (const float*)d_in[2];
  const float* c2w = (const float*)d_in[3];
  const float* c2b = (const float*)d_in[4];
  const float* f1w = (const float*)d_in[5];
  const float* f1b = (const float*)d_in[6];
  const float* f2w = (const float*)d_in[7];
  const float* f2b = (const float*)d_in[8];
  const float* f3w = (const float*)d_in[9];
  const float* f3b = (const float*)d_in[10];
  const float* sup = (const float*)d_in[11];
  float* out = (float*)d_out;

  char* ws = (char*)d_ws;
  float* pool1 = (float*)ws;                     // 46,476,288 B
  float* act   = (float*)(ws + 46476288);        // 28,577,280 B
  float* part  = (float*)(ws + 75053568);        // 13,455,360 B
  float* h1    = (float*)(ws + 88508928);        //     61,440 B

  conv1_pool_kernel<<<dim3(16, 1, BATCH), 256, 0, stream>>>(x, c1w, c1b, pool1);
  conv2_pool_kernel<<<dim3(4, 3, BATCH), 256, 0, stream>>>(pool1, c2w, c2b, act);
  fc1_splitk_kernel<<<NPART, 256, 0, stream>>>(act, f1w, part);
  fc1_reduce_kernel<<<60, 256, 0, stream>>>(part, f1b, h1);
  head_kernel<<<BATCH, 128, 0, stream>>>(h1, f2w, f2b, f3w, f3b, sup, out);
}

// Round 3
// 644.669 us; speedup vs baseline: 1.0742x; 1.0742x over previous
//
#include <hip/hip_runtime.h>
#include <math.h>

// ---------------------------------------------------------------------------
// HybridBinaryClassifier360: conv1(3->6,5x5,s2,p1)+relu+maxpool2s1 ->
// conv2(6->15,3x3,s2,p1)+relu+maxpool2s1 -> fc 55815->120->84->1 ->
// RBF kernel vs 10 supports -> sigmoid -> [p, 1-p].  B=128, fp32.
//
// R3: convs = coalesced LDS staging (stride-1 wave loads, zero-filled halo,
// odd row stride for 4-way-max bank aliasing) + register-tiled conv+pool
// compute (strip of 4 pooled cols, 2 conv rows per thread). No masks/clamps
// in the inner loop. conv2 stages once and loops 2 oc-groups in-block.
// ---------------------------------------------------------------------------

#define BATCH 128

// ---------------- Kernel 1: conv1 + relu + maxpool(2,s1) -------------------
// x [128,3,250,250] -> pool1 [128,6,123,123]
// block 256 = 16 pooled rows x 16 strips(x4 cols). grid (2, 8, 128).
// LDS tile: [3][37][137] (rows 2R0-1..2R0+35, cols 2P0-1..2P0+131, shifted).
#define C1_ST 137   // odd: 2*137=274 = 18 mod 32 -> 16 distinct banks (4-way)
__global__ __launch_bounds__(256) void conv1_pool_kernel(
    const float* __restrict__ x, const float* __restrict__ w,
    const float* __restrict__ bias, float* __restrict__ out) {
  const int b = blockIdx.z;
  const int P0 = blockIdx.x * 64;   // first pooled col of tile
  const int R0 = blockIdx.y * 16;   // first pooled row of tile
  const int tid = threadIdx.x;
  const int t = tid >> 4;           // pooled row 0..15
  const int s = tid & 15;           // strip 0..15 (4 pooled cols each)

  __shared__ float lds[3 * 37 * C1_ST];

  // ---- stage: stride-1 coalesced, zero-filled halo ----
  const int ihb = 2 * R0 - 1, iwb = 2 * P0 - 1;
  for (int i = tid; i < 3 * 37 * 133; i += 256) {
    int il = i % 133;
    int rem = i / 133;
    int lr = rem % 37;
    int ci = rem / 37;
    int ih = ihb + lr, iw = iwb + il;
    float v = 0.f;
    if ((unsigned)ih < 250u && (unsigned)iw < 250u)
      v = x[((b * 3 + ci) * 250 + ih) * 250 + iw];
    lds[(ci * 37 + lr) * C1_ST + il] = v;
  }
  __syncthreads();

  // ---- compute: conv rows r (acc0) and r+1 (acc1), 5 conv cols ----
  float acc0[5][6], acc1[5][6];
#pragma unroll
  for (int oc = 0; oc < 6; oc++) {
    float bv = bias[oc];
#pragma unroll
    for (int dc = 0; dc < 5; dc++) { acc0[dc][oc] = bv; acc1[dc][oc] = bv; }
  }

#pragma unroll 1
  for (int ir = 0; ir < 7; ir++) {
#pragma unroll 1
    for (int ci = 0; ci < 3; ci++) {
      const float* rp = &lds[(ci * 37 + 2 * t + ir) * C1_ST + 8 * s];
      float v[13];
#pragma unroll
      for (int j = 0; j < 13; j++) v[j] = rp[j];

      if (ir < 5) {  // conv row r, kh = ir
#pragma unroll
        for (int oc = 0; oc < 6; oc++) {
          const float* wr = w + ((oc * 3 + ci) * 5 + ir) * 5;
          float w0 = wr[0], w1 = wr[1], w2 = wr[2], w3 = wr[3], w4 = wr[4];
#pragma unroll
          for (int dc = 0; dc < 5; dc++) {
            float a = acc0[dc][oc];
            a += w0 * v[2 * dc + 0];
            a += w1 * v[2 * dc + 1];
            a += w2 * v[2 * dc + 2];
            a += w3 * v[2 * dc + 3];
            a += w4 * v[2 * dc + 4];
            acc0[dc][oc] = a;
          }
        }
      }
      if (ir >= 2) {  // conv row r+1, kh = ir-2
#pragma unroll
        for (int oc = 0; oc < 6; oc++) {
          const float* wr = w + ((oc * 3 + ci) * 5 + (ir - 2)) * 5;
          float w0 = wr[0], w1 = wr[1], w2 = wr[2], w3 = wr[3], w4 = wr[4];
#pragma unroll
          for (int dc = 0; dc < 5; dc++) {
            float a = acc1[dc][oc];
            a += w0 * v[2 * dc + 0];
            a += w1 * v[2 * dc + 1];
            a += w2 * v[2 * dc + 2];
            a += w3 * v[2 * dc + 3];
            a += w4 * v[2 * dc + 4];
            acc1[dc][oc] = a;
          }
        }
      }
    }
  }

  const int r = R0 + t;
  if (r < 123) {
#pragma unroll
    for (int oc = 0; oc < 6; oc++) {
      float* orow = out + ((size_t)(b * 6 + oc) * 123 + r) * 123;
#pragma unroll
      for (int i = 0; i < 4; i++) {
        int c = P0 + 4 * s + i;
        if (c < 123) {
          float m = fmaxf(fmaxf(acc0[i][oc], acc0[i + 1][oc]),
                          fmaxf(acc1[i][oc], acc1[i + 1][oc]));
          orow[c] = fmaxf(m, 0.f);
        }
      }
    }
  }
}

// ---------------- Kernel 2: conv2 + relu + maxpool(2,s1) -------------------
// pool1 [128,6,123,123] -> act [128, 15*61*61] (NCHW flatten)
// block 128 = 8 pooled rows x 16 strips(x4). grid (1, 8, 128).
// LDS tile: [6][19][131]. Two oc-groups {0..7},{7..14} looped in-block.
#define C2_ST 131   // odd: 2*131 = 6 mod 32 -> 16 distinct banks (4-way)
__global__ __launch_bounds__(128) void conv2_pool_kernel(
    const float* __restrict__ in, const float* __restrict__ w,
    const float* __restrict__ bias, float* __restrict__ out) {
  const int b = blockIdx.z;
  const int R0 = blockIdx.y * 8;
  const int tid = threadIdx.x;
  const int t = tid >> 4;           // pooled row 0..7
  const int s = tid & 15;           // strip 0..15

  __shared__ float lds[6 * 19 * C2_ST];

  const int ihb = 2 * R0 - 1;
  for (int i = tid; i < 6 * 19 * 131; i += 128) {
    int il = i % 131;
    int rem = i / 131;
    int lr = rem % 19;
    int ci = rem / 19;
    int ih = ihb + lr, iw = il - 1;
    float v = 0.f;
    if ((unsigned)ih < 123u && (unsigned)iw < 123u)
      v = in[((size_t)(b * 6 + ci) * 123 + ih) * 123 + iw];
    lds[(ci * 19 + lr) * C2_ST + il] = v;
  }
  __syncthreads();

  const int r = R0 + t;

#pragma unroll 1
  for (int ocg = 0; ocg < 2; ocg++) {
    const int oc0 = ocg * 7;  // groups {0..7} and {7..14}; oc 7 done twice
    float acc0[5][8], acc1[5][8];
#pragma unroll
    for (int k = 0; k < 8; k++) {
      float bv = bias[oc0 + k];
#pragma unroll
      for (int dc = 0; dc < 5; dc++) { acc0[dc][k] = bv; acc1[dc][k] = bv; }
    }

#pragma unroll 1
    for (int ir = 0; ir < 5; ir++) {
#pragma unroll 1
      for (int ci = 0; ci < 6; ci++) {
        const float* rp = &lds[(ci * 19 + 2 * t + ir) * C2_ST + 8 * s];
        float v[11];
#pragma unroll
        for (int j = 0; j < 11; j++) v[j] = rp[j];

        if (ir < 3) {  // conv row r, kh = ir
#pragma unroll
          for (int k = 0; k < 8; k++) {
            const float* wr = w + (((oc0 + k) * 6 + ci) * 3 + ir) * 3;
            float w0 = wr[0], w1 = wr[1], w2 = wr[2];
#pragma unroll
            for (int dc = 0; dc < 5; dc++) {
              float a = acc0[dc][k];
              a += w0 * v[2 * dc + 0];
              a += w1 * v[2 * dc + 1];
              a += w2 * v[2 * dc + 2];
              acc0[dc][k] = a;
            }
          }
        }
        if (ir >= 2) {  // conv row r+1, kh = ir-2
#pragma unroll
          for (int k = 0; k < 8; k++) {
            const float* wr = w + (((oc0 + k) * 6 + ci) * 3 + (ir - 2)) * 3;
            float w0 = wr[0], w1 = wr[1], w2 = wr[2];
#pragma unroll
            for (int dc = 0; dc < 5; dc++) {
              float a = acc1[dc][k];
              a += w0 * v[2 * dc + 0];
              a += w1 * v[2 * dc + 1];
              a += w2 * v[2 * dc + 2];
              acc1[dc][k] = a;
            }
          }
        }
      }
    }

    if (r < 61) {
#pragma unroll
      for (int k = 0; k < 8; k++) {
        int oc = oc0 + k;
        float* orow = out + ((size_t)(b * 15 + oc) * 61 + r) * 61;
#pragma unroll
        for (int i = 0; i < 4; i++) {
          int c = 4 * s + i;
          if (c < 61) {
            float m = fmaxf(fmaxf(acc0[i][k], acc0[i + 1][k]),
                            fmaxf(acc1[i][k], acc1[i + 1][k]));
            orow[c] = fmaxf(m, 0.f);
          }
        }
      }
    }
  }
}

// ---------------- Kernel 3: fc1 split-K GEMM partials ----------------------
#define KTOT 55815
#define NPART 219
__global__ __launch_bounds__(256) void fc1_splitk_kernel(
    const float* __restrict__ act, const float* __restrict__ w,
    float* __restrict__ partial) {
  const int kbase = blockIdx.x * 256;
  const int tid = threadIdx.x;
  const int tx = tid % 16, ty = tid / 16;
  __shared__ float ldsA[8 * 132];
  __shared__ float ldsB[8 * 132];
  float acc[8][8];
#pragma unroll
  for (int i = 0; i < 8; i++)
#pragma unroll
    for (int j = 0; j < 8; j++) acc[i][j] = 0.f;

  for (int s8 = 0; s8 < 32; s8++) {
    int kofs = kbase + s8 * 8;
    __syncthreads();
    for (int i = tid; i < 1024; i += 256) {
      int m = i >> 3, kk = i & 7;
      int k = kofs + kk;
      ldsA[kk * 132 + m] = (k < KTOT) ? act[m * KTOT + k] : 0.f;
    }
    for (int i = tid; i < 960; i += 256) {
      int n = i >> 3, kk = i & 7;
      int k = kofs + kk;
      ldsB[kk * 132 + n] = (k < KTOT) ? w[n * KTOT + k] : 0.f;
    }
    __syncthreads();
#pragma unroll
    for (int kk = 0; kk < 8; kk++) {
      float4 a0 = *(const float4*)&ldsA[kk * 132 + ty * 8];
      float4 a1 = *(const float4*)&ldsA[kk * 132 + ty * 8 + 4];
      float4 b0 = *(const float4*)&ldsB[kk * 132 + tx * 8];
      float4 b1 = *(const float4*)&ldsB[kk * 132 + tx * 8 + 4];
      float av[8] = {a0.x, a0.y, a0.z, a0.w, a1.x, a1.y, a1.z, a1.w};
      float bv[8] = {b0.x, b0.y, b0.z, b0.w, b1.x, b1.y, b1.z, b1.w};
#pragma unroll
      for (int i = 0; i < 8; i++)
#pragma unroll
        for (int j = 0; j < 8; j++) acc[i][j] += av[i] * bv[j];
    }
  }

  float* dst = partial + (size_t)blockIdx.x * 15360;
#pragma unroll
  for (int i = 0; i < 8; i++) {
    int row = ty * 8 + i;
#pragma unroll
    for (int j = 0; j < 8; j++) {
      int col = tx * 8 + j;
      if (col < 120) dst[row * 120 + col] = acc[i][j];
    }
  }
}

// ---------------- Kernel 4: reduce partials + bias + relu ------------------
__global__ __launch_bounds__(256) void fc1_reduce_kernel(
    const float* __restrict__ partial, const float* __restrict__ bias,
    float* __restrict__ h1) {
  int idx = blockIdx.x * 256 + threadIdx.x;
  if (idx >= 15360) return;
  float s = 0.f;
  for (int p = 0; p < NPART; p++) s += partial[(size_t)p * 15360 + idx];
  h1[idx] = fmaxf(s + bias[idx % 120], 0.f);
}

// ---------------- Kernel 5: fc2 + fc3 + RBF + sigmoid ----------------------
__global__ __launch_bounds__(128) void head_kernel(
    const float* __restrict__ h1, const float* __restrict__ fc2_w,
    const float* __restrict__ fc2_b, const float* __restrict__ fc3_w,
    const float* __restrict__ fc3_b, const float* __restrict__ support,
    float* __restrict__ out) {
  int b = blockIdx.x, t = threadIdx.x;
  __shared__ float hrow[120];
  __shared__ float s2[84];
  if (t < 120) hrow[t] = h1[b * 120 + t];
  __syncthreads();
  if (t < 84) {
    float d = fc2_b[t];
    for (int k = 0; k < 120; k++) d += fc2_w[t * 120 + k] * hrow[k];
    s2[t] = fmaxf(d, 0.f);
  }
  __syncthreads();
  if (t == 0) {
    float h = fc3_b[0];
    for (int j = 0; j < 84; j++) h += fc3_w[j] * s2[j];
    float ks = 0.f;
    for (int j = 0; j < 10; j++) {
      float diff = h - support[j];
      ks += expf(-diff * diff);
    }
    ks *= 0.1f;
    float p = 1.f / (1.f + expf(-ks));
    out[b * 2] = p;
    out[b * 2 + 1] = 1.f - p;
  }
}

// ---------------------------------------------------------------------------
extern "C" void kernel_launch(void* const* d_in, const int* in_sizes, int n_in,
                              void* d_out, int out_size, void* d_ws, size_t ws_size,
                              hipStream_t stream) {
  const float* x   = (const float*)d_in[0];
  const float* c1w = (const float*)d_in[1];
  const float* c1b = (const float*)d_in[2];
  const float* c2w = (const float*)d_in[3];
  const float* c2b = (const float*)d_in[4];
  const float* f1w = (const float*)d_in[5];
  const float* f1b = (const float*)d_in[6];
  const float* f2w = (const float*)d_in[7];
  const float* f2b = (const float*)d_in[8];
  const float* f3w = (const float*)d_in[9];
  const float* f3b = (const float*)d_in[10];
  const float* sup = (const float*)d_in[11];
  float* out = (float*)d_out;

  char* ws = (char*)d_ws;
  float* pool1 = (float*)ws;                     // 46,476,288 B
  float* act   = (float*)(ws + 46476288);        // 28,577,280 B
  float* part  = (float*)(ws + 75053568);        // 13,455,360 B
  float* h1    = (float*)(ws + 88508928);        //     61,440 B

  conv1_pool_kernel<<<dim3(2, 8, BATCH), 256, 0, stream>>>(x, c1w, c1b, pool1);
  conv2_pool_kernel<<<dim3(1, 8, BATCH), 128, 0, stream>>>(pool1, c2w, c2b, act);
  fc1_splitk_kernel<<<NPART, 256, 0, stream>>>(act, f1w, part);
  fc1_reduce_kernel<<<60, 256, 0, stream>>>(part, f1b, h1);
  head_kernel<<<BATCH, 128, 0, stream>>>(h1, f2w, f2b, f3w, f3b, sup, out);
}

// Round 4
// 543.245 us; speedup vs baseline: 1.2747x; 1.1867x over previous
//
#include <hip/hip_runtime.h>
#include <math.h>

// ---------------------------------------------------------------------------
// HybridBinaryClassifier360: conv1(3->6,5x5,s2,p1)+relu+maxpool2s1 ->
// conv2(6->15,3x3,s2,p1)+relu+maxpool2s1 -> fc 55815->120->84->1 ->
// RBF kernel vs 10 supports -> sigmoid -> [p, 1-p].  B=128, fp32.
//
// R4: occupancy push. All conv tiles sized for ~31 KB LDS -> 5 blocks/CU
// (was 2). fc1 split-K widened to 512 blocks (2/CU, balanced), partials
// reuse pool1's dead workspace region. reduce spread over 240 blocks.
// ---------------------------------------------------------------------------

#define BATCH 128

// ---------------- Kernel 1: conv1 + relu + maxpool(2,s1) -------------------
// x [128,3,250,250] -> pool1 [128,6,123,123]
// tile: 8 pooled rows x 64 pooled cols; block 128 = 8 rows x 16 strips(x4).
// LDS [3][19][136] (133 cols used). grid (2, 16, 128). 31 KB -> 5 blocks/CU.
#define C1_ST 136
__global__ __launch_bounds__(128) void conv1_pool_kernel(
    const float* __restrict__ x, const float* __restrict__ w,
    const float* __restrict__ bias, float* __restrict__ out) {
  const int b = blockIdx.z;
  const int P0 = blockIdx.x * 64;
  const int R0 = blockIdx.y * 8;
  const int tid = threadIdx.x;
  const int t = tid >> 4;           // pooled row 0..7
  const int s = tid & 15;           // strip 0..15 (4 pooled cols)

  __shared__ float lds[3 * 19 * C1_ST];

  const int ihb = 2 * R0 - 1, iwb = 2 * P0 - 1;
  for (int i = tid; i < 3 * 19 * 133; i += 128) {
    int il = i % 133;
    int rem = i / 133;
    int lr = rem % 19;
    int ci = rem / 19;
    int ih = ihb + lr, iw = iwb + il;
    float v = 0.f;
    if ((unsigned)ih < 250u && (unsigned)iw < 250u)
      v = x[((b * 3 + ci) * 250 + ih) * 250 + iw];
    lds[(ci * 19 + lr) * C1_ST + il] = v;
  }
  __syncthreads();

  float acc0[5][6], acc1[5][6];   // conv rows r, r+1 x 5 conv cols x 6 oc
#pragma unroll
  for (int oc = 0; oc < 6; oc++) {
    float bv = bias[oc];
#pragma unroll
    for (int dc = 0; dc < 5; dc++) { acc0[dc][oc] = bv; acc1[dc][oc] = bv; }
  }

#pragma unroll 1
  for (int ir = 0; ir < 7; ir++) {
#pragma unroll 1
    for (int ci = 0; ci < 3; ci++) {
      const float* rp = &lds[(ci * 19 + 2 * t + ir) * C1_ST + 8 * s];
      float v[13];
#pragma unroll
      for (int j = 0; j < 13; j++) v[j] = rp[j];

      if (ir < 5) {
#pragma unroll
        for (int oc = 0; oc < 6; oc++) {
          const float* wr = w + ((oc * 3 + ci) * 5 + ir) * 5;
          float w0 = wr[0], w1 = wr[1], w2 = wr[2], w3 = wr[3], w4 = wr[4];
#pragma unroll
          for (int dc = 0; dc < 5; dc++) {
            float a = acc0[dc][oc];
            a += w0 * v[2 * dc + 0];
            a += w1 * v[2 * dc + 1];
            a += w2 * v[2 * dc + 2];
            a += w3 * v[2 * dc + 3];
            a += w4 * v[2 * dc + 4];
            acc0[dc][oc] = a;
          }
        }
      }
      if (ir >= 2) {
#pragma unroll
        for (int oc = 0; oc < 6; oc++) {
          const float* wr = w + ((oc * 3 + ci) * 5 + (ir - 2)) * 5;
          float w0 = wr[0], w1 = wr[1], w2 = wr[2], w3 = wr[3], w4 = wr[4];
#pragma unroll
          for (int dc = 0; dc < 5; dc++) {
            float a = acc1[dc][oc];
            a += w0 * v[2 * dc + 0];
            a += w1 * v[2 * dc + 1];
            a += w2 * v[2 * dc + 2];
            a += w3 * v[2 * dc + 3];
            a += w4 * v[2 * dc + 4];
            acc1[dc][oc] = a;
          }
        }
      }
    }
  }

  const int r = R0 + t;
  if (r < 123) {
#pragma unroll
    for (int oc = 0; oc < 6; oc++) {
      float* orow = out + ((size_t)(b * 6 + oc) * 123 + r) * 123;
#pragma unroll
      for (int i = 0; i < 4; i++) {
        int c = P0 + 4 * s + i;
        if (c < 123) {
          float m = fmaxf(fmaxf(acc0[i][oc], acc0[i + 1][oc]),
                          fmaxf(acc1[i][oc], acc1[i + 1][oc]));
          orow[c] = fmaxf(m, 0.f);
        }
      }
    }
  }
}

// ---------------- Kernel 2: conv2 + relu + maxpool(2,s1) -------------------
// pool1 [128,6,123,123] -> act [128, 15*61*61] (NCHW flatten)
// tile: 8 pooled rows x 32 pooled cols; block 128 = 8 rows x 16 strips(x2).
// LDS [6][19][68] (67 cols used) = 31 KB -> 5 blocks/CU. grid (2, 8, 128).
// Two oc-groups {0..7},{7..14} looped in-block.
#define C2_ST 68
__global__ __launch_bounds__(128) void conv2_pool_kernel(
    const float* __restrict__ in, const float* __restrict__ w,
    const float* __restrict__ bias, float* __restrict__ out) {
  const int b = blockIdx.z;
  const int P0 = blockIdx.x * 32;
  const int R0 = blockIdx.y * 8;
  const int tid = threadIdx.x;
  const int t = tid >> 4;           // pooled row 0..7
  const int s = tid & 15;           // strip 0..15 (2 pooled cols)

  __shared__ float lds[6 * 19 * C2_ST];

  const int ihb = 2 * R0 - 1, iwb = 2 * P0 - 1;
  for (int i = tid; i < 6 * 19 * 67; i += 128) {
    int il = i % 67;
    int rem = i / 67;
    int lr = rem % 19;
    int ci = rem / 19;
    int ih = ihb + lr, iw = iwb + il;
    float v = 0.f;
    if ((unsigned)ih < 123u && (unsigned)iw < 123u)
      v = in[((size_t)(b * 6 + ci) * 123 + ih) * 123 + iw];
    lds[(ci * 19 + lr) * C2_ST + il] = v;
  }
  __syncthreads();

  const int r = R0 + t;

#pragma unroll 1
  for (int ocg = 0; ocg < 2; ocg++) {
    const int oc0 = ocg * 7;        // {0..7}, {7..14}; oc 7 computed twice
    float acc0[3][8], acc1[3][8];   // conv rows r, r+1 x 3 conv cols x 8 oc
#pragma unroll
    for (int k = 0; k < 8; k++) {
      float bv = bias[oc0 + k];
#pragma unroll
      for (int dc = 0; dc < 3; dc++) { acc0[dc][k] = bv; acc1[dc][k] = bv; }
    }

#pragma unroll 1
    for (int ir = 0; ir < 5; ir++) {
#pragma unroll 1
      for (int ci = 0; ci < 6; ci++) {
        const float* rp = &lds[(ci * 19 + 2 * t + ir) * C2_ST + 4 * s];
        float v[7];
#pragma unroll
        for (int j = 0; j < 7; j++) v[j] = rp[j];

        if (ir < 3) {   // conv row r, kh = ir
#pragma unroll
          for (int k = 0; k < 8; k++) {
            const float* wr = w + (((oc0 + k) * 6 + ci) * 3 + ir) * 3;
            float w0 = wr[0], w1 = wr[1], w2 = wr[2];
#pragma unroll
            for (int dc = 0; dc < 3; dc++) {
              float a = acc0[dc][k];
              a += w0 * v[2 * dc + 0];
              a += w1 * v[2 * dc + 1];
              a += w2 * v[2 * dc + 2];
              acc0[dc][k] = a;
            }
          }
        }
        if (ir >= 2) {  // conv row r+1, kh = ir-2
#pragma unroll
          for (int k = 0; k < 8; k++) {
            const float* wr = w + (((oc0 + k) * 6 + ci) * 3 + (ir - 2)) * 3;
            float w0 = wr[0], w1 = wr[1], w2 = wr[2];
#pragma unroll
            for (int dc = 0; dc < 3; dc++) {
              float a = acc1[dc][k];
              a += w0 * v[2 * dc + 0];
              a += w1 * v[2 * dc + 1];
              a += w2 * v[2 * dc + 2];
              acc1[dc][k] = a;
            }
          }
        }
      }
    }

    if (r < 61) {
#pragma unroll
      for (int k = 0; k < 8; k++) {
        int oc = oc0 + k;
        float* orow = out + ((size_t)(b * 15 + oc) * 61 + r) * 61;
#pragma unroll
        for (int i = 0; i < 2; i++) {
          int c = P0 + 2 * s + i;
          if (c < 61) {
            float m = fmaxf(fmaxf(acc0[i][k], acc0[i + 1][k]),
                            fmaxf(acc1[i][k], acc1[i + 1][k]));
            orow[c] = fmaxf(m, 0.f);
          }
        }
      }
    }
  }
}

// ---------------- Kernel 3: fc1 split-K GEMM partials ----------------------
// C[128,120] = act[128,55815] @ fc1_w[120,55815]^T
// 512 blocks, K-chunk 112 (14 steps of 8). 2 blocks/CU.
#define KTOT 55815
#define NPART 512
#define KCHUNK 112
__global__ __launch_bounds__(256) void fc1_splitk_kernel(
    const float* __restrict__ act, const float* __restrict__ w,
    float* __restrict__ partial) {
  const int kbase = blockIdx.x * KCHUNK;
  const int tid = threadIdx.x;
  const int tx = tid % 16, ty = tid / 16;
  __shared__ float ldsA[8 * 132];
  __shared__ float ldsB[8 * 132];
  float acc[8][8];
#pragma unroll
  for (int i = 0; i < 8; i++)
#pragma unroll
    for (int j = 0; j < 8; j++) acc[i][j] = 0.f;

  for (int s8 = 0; s8 < KCHUNK / 8; s8++) {
    int kofs = kbase + s8 * 8;
    __syncthreads();
    for (int i = tid; i < 1024; i += 256) {
      int m = i >> 3, kk = i & 7;
      int k = kofs + kk;
      ldsA[kk * 132 + m] = (k < KTOT) ? act[m * KTOT + k] : 0.f;
    }
    for (int i = tid; i < 960; i += 256) {
      int n = i >> 3, kk = i & 7;
      int k = kofs + kk;
      ldsB[kk * 132 + n] = (k < KTOT) ? w[n * KTOT + k] : 0.f;
    }
    __syncthreads();
#pragma unroll
    for (int kk = 0; kk < 8; kk++) {
      float4 a0 = *(const float4*)&ldsA[kk * 132 + ty * 8];
      float4 a1 = *(const float4*)&ldsA[kk * 132 + ty * 8 + 4];
      float4 b0 = *(const float4*)&ldsB[kk * 132 + tx * 8];
      float4 b1 = *(const float4*)&ldsB[kk * 132 + tx * 8 + 4];
      float av[8] = {a0.x, a0.y, a0.z, a0.w, a1.x, a1.y, a1.z, a1.w};
      float bv[8] = {b0.x, b0.y, b0.z, b0.w, b1.x, b1.y, b1.z, b1.w};
#pragma unroll
      for (int i = 0; i < 8; i++)
#pragma unroll
        for (int j = 0; j < 8; j++) acc[i][j] += av[i] * bv[j];
    }
  }

  float* dst = partial + (size_t)blockIdx.x * 15360;
#pragma unroll
  for (int i = 0; i < 8; i++) {
    int row = ty * 8 + i;
#pragma unroll
    for (int j = 0; j < 8; j++) {
      int col = tx * 8 + j;
      if (col < 120) dst[row * 120 + col] = acc[i][j];
    }
  }
}

// ---------------- Kernel 4: reduce partials + bias + relu ------------------
__global__ __launch_bounds__(64) void fc1_reduce_kernel(
    const float* __restrict__ partial, const float* __restrict__ bias,
    float* __restrict__ h1) {
  int idx = blockIdx.x * 64 + threadIdx.x;
  if (idx >= 15360) return;
  float s = 0.f;
  for (int p = 0; p < NPART; p++) s += partial[(size_t)p * 15360 + idx];
  h1[idx] = fmaxf(s + bias[idx % 120], 0.f);
}

// ---------------- Kernel 5: fc2 + fc3 + RBF + sigmoid ----------------------
__global__ __launch_bounds__(128) void head_kernel(
    const float* __restrict__ h1, const float* __restrict__ fc2_w,
    const float* __restrict__ fc2_b, const float* __restrict__ fc3_w,
    const float* __restrict__ fc3_b, const float* __restrict__ support,
    float* __restrict__ out) {
  int b = blockIdx.x, t = threadIdx.x;
  __shared__ float hrow[120];
  __shared__ float s2[84];
  if (t < 120) hrow[t] = h1[b * 120 + t];
  __syncthreads();
  if (t < 84) {
    float d = fc2_b[t];
    for (int k = 0; k < 120; k++) d += fc2_w[t * 120 + k] * hrow[k];
    s2[t] = fmaxf(d, 0.f);
  }
  __syncthreads();
  if (t == 0) {
    float h = fc3_b[0];
    for (int j = 0; j < 84; j++) h += fc3_w[j] * s2[j];
    float ks = 0.f;
    for (int j = 0; j < 10; j++) {
      float diff = h - support[j];
      ks += expf(-diff * diff);
    }
    ks *= 0.1f;
    float p = 1.f / (1.f + expf(-ks));
    out[b * 2] = p;
    out[b * 2 + 1] = 1.f - p;
  }
}

// ---------------------------------------------------------------------------
extern "C" void kernel_launch(void* const* d_in, const int* in_sizes, int n_in,
                              void* d_out, int out_size, void* d_ws, size_t ws_size,
                              hipStream_t stream) {
  const float* x   = (const float*)d_in[0];
  const float* c1w = (const float*)d_in[1];
  const float* c1b = (const float*)d_in[2];
  const float* c2w = (const float*)d_in[3];
  const float* c2b = (const float*)d_in[4];
  const float* f1w = (const float*)d_in[5];
  const float* f1b = (const float*)d_in[6];
  const float* f2w = (const float*)d_in[7];
  const float* f2b = (const float*)d_in[8];
  const float* f3w = (const float*)d_in[9];
  const float* f3b = (const float*)d_in[10];
  const float* sup = (const float*)d_in[11];
  float* out = (float*)d_out;

  char* ws = (char*)d_ws;
  // Lifetimes: pool1 [0, 46.5 MB) dead after conv2 -> partials reuse it.
  float* pool1 = (float*)ws;                     // 46,476,288 B
  float* act   = (float*)(ws + 46476288);        // 28,577,280 B
  float* part  = (float*)ws;                     // 512*15360*4 = 31,457,280 B
  float* h1    = (float*)(ws + 33000000);        //     61,440 B (inside dead pool1)

  conv1_pool_kernel<<<dim3(2, 16, BATCH), 128, 0, stream>>>(x, c1w, c1b, pool1);
  conv2_pool_kernel<<<dim3(2, 8, BATCH), 128, 0, stream>>>(pool1, c2w, c2b, act);
  fc1_splitk_kernel<<<NPART, 256, 0, stream>>>(act, f1w, part);
  fc1_reduce_kernel<<<240, 64, 0, stream>>>(part, f1b, h1);
  head_kernel<<<BATCH, 128, 0, stream>>>(h1, f2w, f2b, f3w, f3b, sup, out);
}

// Round 5
// 381.999 us; speedup vs baseline: 1.8128x; 1.4221x over previous
//
#include <hip/hip_runtime.h>
#include <math.h>

// ---------------------------------------------------------------------------
// HybridBinaryClassifier360: conv1(3->6,5x5,s2,p1)+relu+maxpool2s1 ->
// conv2(6->15,3x3,s2,p1)+relu+maxpool2s1 -> fc 55815->120->84->1 ->
// RBF kernel vs 10 supports -> sigmoid -> [p, 1-p].  B=128, fp32.
//
// R5: per-ci LDS slicing (22 KB / 12 KB -> 5-7 blocks/CU), skewed LDS layout
// (col + col>>3) so strip reads hit 16 distinct banks, 8-deep batched
// staging loads, conv2 single-pass over all 15 oc, two-stage fc1 reduce.
// Fixes R4 latent bug: conv1 tile must stage 37 rows (2t+ir max 36).
// ---------------------------------------------------------------------------

#define BATCH 128

// ---------------- Kernel 1: conv1 + relu + maxpool(2,s1) -------------------
// x [128,3,250,250] -> pool1 [128,6,123,123]
// tile: 16 pooled rows x 64 pooled cols; block 256 = 16 rows x 16 strips(x4).
// Per-ci LDS slice [37][150] (133 cols used, skew col+col>>3) = 22.2 KB.
// grid (2, 8, 128).
#define C1_ST 150
#define C1_TOT (37 * 133)   // 4921
__global__ __launch_bounds__(256) void conv1_pool_kernel(
    const float* __restrict__ x, const float* __restrict__ w,
    const float* __restrict__ bias, float* __restrict__ out) {
  const int b = blockIdx.z;
  const int P0 = blockIdx.x * 64;
  const int R0 = blockIdx.y * 16;
  const int tid = threadIdx.x;
  const int t = tid >> 4;           // pooled row 0..15
  const int s = tid & 15;           // strip 0..15 (4 pooled cols)

  __shared__ float lds[37 * C1_ST];

  float acc0[5][6], acc1[5][6];     // conv rows r, r+1 x 5 conv cols x 6 oc
#pragma unroll
  for (int oc = 0; oc < 6; oc++) {
    float bv = bias[oc];
#pragma unroll
    for (int dc = 0; dc < 5; dc++) { acc0[dc][oc] = bv; acc1[dc][oc] = bv; }
  }

  const int ihb = 2 * R0 - 1, iwb = 2 * P0 - 1;

#pragma unroll 1
  for (int ci = 0; ci < 3; ci++) {
    __syncthreads();                 // WAR: previous ci's compute done
    const float* src = x + (size_t)(b * 3 + ci) * 62500;
    // batched staging: 8 independent loads, then 8 LDS writes
#pragma unroll 1
    for (int base = tid; base < C1_TOT; base += 2048) {
      float vv[8];
#pragma unroll
      for (int k = 0; k < 8; k++) {
        int i = base + (k << 8);
        int lr = i / 133, il = i - lr * 133;
        int ih = ihb + lr, iw = iwb + il;
        bool ok = (i < C1_TOT) && ((unsigned)ih < 250u) && ((unsigned)iw < 250u);
        vv[k] = ok ? src[ih * 250 + iw] : 0.f;
      }
#pragma unroll
      for (int k = 0; k < 8; k++) {
        int i = base + (k << 8);
        if (i < C1_TOT) {
          int lr = i / 133, il = i - lr * 133;
          lds[lr * C1_ST + il + (il >> 3)] = vv[k];
        }
      }
    }
    __syncthreads();                 // RAW: staging visible

#pragma unroll 1
    for (int ir = 0; ir < 7; ir++) {
      const float* rp = &lds[(2 * t + ir) * C1_ST + 9 * s];
      float v[13];
#pragma unroll
      for (int j = 0; j < 13; j++) v[j] = rp[j + (j >> 3)];

      if (ir < 5) {                  // conv row r, kh = ir
#pragma unroll
        for (int oc = 0; oc < 6; oc++) {
          const float* wr = w + ((oc * 3 + ci) * 5 + ir) * 5;
          float w0 = wr[0], w1 = wr[1], w2 = wr[2], w3 = wr[3], w4 = wr[4];
#pragma unroll
          for (int dc = 0; dc < 5; dc++) {
            float a = acc0[dc][oc];
            a += w0 * v[2 * dc + 0];
            a += w1 * v[2 * dc + 1];
            a += w2 * v[2 * dc + 2];
            a += w3 * v[2 * dc + 3];
            a += w4 * v[2 * dc + 4];
            acc0[dc][oc] = a;
          }
        }
      }
      if (ir >= 2) {                 // conv row r+1, kh = ir-2
#pragma unroll
        for (int oc = 0; oc < 6; oc++) {
          const float* wr = w + ((oc * 3 + ci) * 5 + (ir - 2)) * 5;
          float w0 = wr[0], w1 = wr[1], w2 = wr[2], w3 = wr[3], w4 = wr[4];
#pragma unroll
          for (int dc = 0; dc < 5; dc++) {
            float a = acc1[dc][oc];
            a += w0 * v[2 * dc + 0];
            a += w1 * v[2 * dc + 1];
            a += w2 * v[2 * dc + 2];
            a += w3 * v[2 * dc + 3];
            a += w4 * v[2 * dc + 4];
            acc1[dc][oc] = a;
          }
        }
      }
    }
  }

  const int r = R0 + t;
  if (r < 123) {
#pragma unroll
    for (int oc = 0; oc < 6; oc++) {
      float* orow = out + ((size_t)(b * 6 + oc) * 123 + r) * 123;
#pragma unroll
      for (int i = 0; i < 4; i++) {
        int c = P0 + 4 * s + i;
        if (c < 123) {
          float m = fmaxf(fmaxf(acc0[i][oc], acc0[i + 1][oc]),
                          fmaxf(acc1[i][oc], acc1[i + 1][oc]));
          orow[c] = fmaxf(m, 0.f);
        }
      }
    }
  }
}

// ---------------- Kernel 2: conv2 + relu + maxpool(2,s1) -------------------
// pool1 [128,6,123,123] -> act [128, 15*61*61] (NCHW flatten)
// tile: 16 pooled rows x 32 pooled cols; block 256 = 16 rows x 16 strips(x2).
// Per-ci LDS slice [35][84] (67 cols used, skew col+col>>2) = 11.8 KB.
// Single pass over all 15 oc. grid (2, 4, 128).
#define C2_ST 84
#define C2_TOT (35 * 67)    // 2345
__global__ __launch_bounds__(256) void conv2_pool_kernel(
    const float* __restrict__ in, const float* __restrict__ w,
    const float* __restrict__ bias, float* __restrict__ out) {
  const int b = blockIdx.z;
  const int P0 = blockIdx.x * 32;
  const int R0 = blockIdx.y * 16;
  const int tid = threadIdx.x;
  const int t = tid >> 4;           // pooled row 0..15
  const int s = tid & 15;           // strip 0..15 (2 pooled cols)

  __shared__ float lds[35 * C2_ST];

  float acc0[3][15], acc1[3][15];   // conv rows r, r+1 x 3 conv cols x 15 oc
#pragma unroll
  for (int k = 0; k < 15; k++) {
    float bv = bias[k];
#pragma unroll
    for (int dc = 0; dc < 3; dc++) { acc0[dc][k] = bv; acc1[dc][k] = bv; }
  }

  const int ihb = 2 * R0 - 1, iwb = 2 * P0 - 1;

#pragma unroll 1
  for (int ci = 0; ci < 6; ci++) {
    __syncthreads();
    const float* src = in + (size_t)(b * 6 + ci) * 15129;  // 123*123
#pragma unroll 1
    for (int base = tid; base < C2_TOT; base += 2048) {
      float vv[8];
#pragma unroll
      for (int k = 0; k < 8; k++) {
        int i = base + (k << 8);
        int lr = i / 67, il = i - lr * 67;
        int ih = ihb + lr, iw = iwb + il;
        bool ok = (i < C2_TOT) && ((unsigned)ih < 123u) && ((unsigned)iw < 123u);
        vv[k] = ok ? src[ih * 123 + iw] : 0.f;
      }
#pragma unroll
      for (int k = 0; k < 8; k++) {
        int i = base + (k << 8);
        if (i < C2_TOT) {
          int lr = i / 67, il = i - lr * 67;
          lds[lr * C2_ST + il + (il >> 2)] = vv[k];
        }
      }
    }
    __syncthreads();

#pragma unroll 1
    for (int ir = 0; ir < 5; ir++) {
      const float* rp = &lds[(2 * t + ir) * C2_ST + 5 * s];
      float v[7];
#pragma unroll
      for (int j = 0; j < 7; j++) v[j] = rp[j + (j >> 2)];

      if (ir < 3) {                  // conv row r, kh = ir
#pragma unroll
        for (int k = 0; k < 15; k++) {
          const float* wr = w + ((k * 6 + ci) * 3 + ir) * 3;
          float w0 = wr[0], w1 = wr[1], w2 = wr[2];
#pragma unroll
          for (int dc = 0; dc < 3; dc++) {
            float a = acc0[dc][k];
            a += w0 * v[2 * dc + 0];
            a += w1 * v[2 * dc + 1];
            a += w2 * v[2 * dc + 2];
            acc0[dc][k] = a;
          }
        }
      }
      if (ir >= 2) {                 // conv row r+1, kh = ir-2
#pragma unroll
        for (int k = 0; k < 15; k++) {
          const float* wr = w + ((k * 6 + ci) * 3 + (ir - 2)) * 3;
          float w0 = wr[0], w1 = wr[1], w2 = wr[2];
#pragma unroll
          for (int dc = 0; dc < 3; dc++) {
            float a = acc1[dc][k];
            a += w0 * v[2 * dc + 0];
            a += w1 * v[2 * dc + 1];
            a += w2 * v[2 * dc + 2];
            acc1[dc][k] = a;
          }
        }
      }
    }
  }

  const int r = R0 + t;
  if (r < 61) {
#pragma unroll
    for (int k = 0; k < 15; k++) {
      float* orow = out + ((size_t)(b * 15 + k) * 61 + r) * 61;
#pragma unroll
      for (int i = 0; i < 2; i++) {
        int c = P0 + 2 * s + i;
        if (c < 61) {
          float m = fmaxf(fmaxf(acc0[i][k], acc0[i + 1][k]),
                          fmaxf(acc1[i][k], acc1[i + 1][k]));
          orow[c] = fmaxf(m, 0.f);
        }
      }
    }
  }
}

// ---------------- Kernel 3: fc1 split-K GEMM partials ----------------------
// C[128,120] = act[128,55815] @ fc1_w[120,55815]^T
// 512 blocks, K-chunk 112 (14 steps of 8). 2 blocks/CU.
#define KTOT 55815
#define NPART 512
#define KCHUNK 112
__global__ __launch_bounds__(256) void fc1_splitk_kernel(
    const float* __restrict__ act, const float* __restrict__ w,
    float* __restrict__ partial) {
  const int kbase = blockIdx.x * KCHUNK;
  const int tid = threadIdx.x;
  const int tx = tid % 16, ty = tid / 16;
  __shared__ float ldsA[8 * 132];
  __shared__ float ldsB[8 * 132];
  float acc[8][8];
#pragma unroll
  for (int i = 0; i < 8; i++)
#pragma unroll
    for (int j = 0; j < 8; j++) acc[i][j] = 0.f;

  for (int s8 = 0; s8 < KCHUNK / 8; s8++) {
    int kofs = kbase + s8 * 8;
    __syncthreads();
    for (int i = tid; i < 1024; i += 256) {
      int m = i >> 3, kk = i & 7;
      int k = kofs + kk;
      ldsA[kk * 132 + m] = (k < KTOT) ? act[m * KTOT + k] : 0.f;
    }
    for (int i = tid; i < 960; i += 256) {
      int n = i >> 3, kk = i & 7;
      int k = kofs + kk;
      ldsB[kk * 132 + n] = (k < KTOT) ? w[n * KTOT + k] : 0.f;
    }
    __syncthreads();
#pragma unroll
    for (int kk = 0; kk < 8; kk++) {
      float4 a0 = *(const float4*)&ldsA[kk * 132 + ty * 8];
      float4 a1 = *(const float4*)&ldsA[kk * 132 + ty * 8 + 4];
      float4 b0 = *(const float4*)&ldsB[kk * 132 + tx * 8];
      float4 b1 = *(const float4*)&ldsB[kk * 132 + tx * 8 + 4];
      float av[8] = {a0.x, a0.y, a0.z, a0.w, a1.x, a1.y, a1.z, a1.w};
      float bv[8] = {b0.x, b0.y, b0.z, b0.w, b1.x, b1.y, b1.z, b1.w};
#pragma unroll
      for (int i = 0; i < 8; i++)
#pragma unroll
        for (int j = 0; j < 8; j++) acc[i][j] += av[i] * bv[j];
    }
  }

  float* dst = partial + (size_t)blockIdx.x * 15360;
#pragma unroll
  for (int i = 0; i < 8; i++) {
    int row = ty * 8 + i;
#pragma unroll
    for (int j = 0; j < 8; j++) {
      int col = tx * 8 + j;
      if (col < 120) dst[row * 120 + col] = acc[i][j];
    }
  }
}

// ---------------- Kernel 4a/4b: two-stage reduce + bias + relu -------------
// stage 1: partial2[g][idx] = sum_{p in [64g, 64g+64)} partial[p][idx]
__global__ __launch_bounds__(64) void fc1_reduce1_kernel(
    const float* __restrict__ partial, float* __restrict__ partial2) {
  int idx = blockIdx.x * 64 + threadIdx.x;   // 0..15359
  int g = blockIdx.y;                        // 0..7
  const float* p = partial + (size_t)g * 64 * 15360 + idx;
  float s = 0.f;
#pragma unroll 8
  for (int q = 0; q < 64; q++) s += p[(size_t)q * 15360];
  partial2[(size_t)g * 15360 + idx] = s;
}

__global__ __launch_bounds__(64) void fc1_reduce2_kernel(
    const float* __restrict__ partial2, const float* __restrict__ bias,
    float* __restrict__ h1) {
  int idx = blockIdx.x * 64 + threadIdx.x;
  float s = 0.f;
#pragma unroll
  for (int g = 0; g < 8; g++) s += partial2[(size_t)g * 15360 + idx];
  h1[idx] = fmaxf(s + bias[idx % 120], 0.f);
}

// ---------------- Kernel 5: fc2 + fc3 + RBF + sigmoid ----------------------
__global__ __launch_bounds__(128) void head_kernel(
    const float* __restrict__ h1, const float* __restrict__ fc2_w,
    const float* __restrict__ fc2_b, const float* __restrict__ fc3_w,
    const float* __restrict__ fc3_b, const float* __restrict__ support,
    float* __restrict__ out) {
  int b = blockIdx.x, t = threadIdx.x;
  __shared__ float hrow[120];
  __shared__ float s2[84];
  if (t < 120) hrow[t] = h1[b * 120 + t];
  __syncthreads();
  if (t < 84) {
    float d = fc2_b[t];
    for (int k = 0; k < 120; k++) d += fc2_w[t * 120 + k] * hrow[k];
    s2[t] = fmaxf(d, 0.f);
  }
  __syncthreads();
  if (t == 0) {
    float h = fc3_b[0];
    for (int j = 0; j < 84; j++) h += fc3_w[j] * s2[j];
    float ks = 0.f;
    for (int j = 0; j < 10; j++) {
      float diff = h - support[j];
      ks += expf(-diff * diff);
    }
    ks *= 0.1f;
    float p = 1.f / (1.f + expf(-ks));
    out[b * 2] = p;
    out[b * 2 + 1] = 1.f - p;
  }
}

// ---------------------------------------------------------------------------
extern "C" void kernel_launch(void* const* d_in, const int* in_sizes, int n_in,
                              void* d_out, int out_size, void* d_ws, size_t ws_size,
                              hipStream_t stream) {
  const float* x   = (const float*)d_in[0];
  const float* c1w = (const float*)d_in[1];
  const float* c1b = (const float*)d_in[2];
  const float* c2w = (const float*)d_in[3];
  const float* c2b = (const float*)d_in[4];
  const float* f1w = (const float*)d_in[5];
  const float* f1b = (const float*)d_in[6];
  const float* f2w = (const float*)d_in[7];
  const float* f2b = (const float*)d_in[8];
  const float* f3w = (const float*)d_in[9];
  const float* f3b = (const float*)d_in[10];
  const float* sup = (const float*)d_in[11];
  float* out = (float*)d_out;

  char* ws = (char*)d_ws;
  // Lifetimes: pool1 [0,46.5MB) dead after conv2 -> part/partial2/h1 reuse it.
  float* pool1 = (float*)ws;                     // 46,476,288 B
  float* act   = (float*)(ws + 46476288);        // 28,577,280 B (alive thru fc1)
  float* part  = (float*)ws;                     // 512*15360*4 = 31,457,280 B
  float* h1    = (float*)(ws + 33000000);        //     61,440 B
  float* part2 = (float*)(ws + 34000000);        //  8*15360*4 = 491,520 B

  conv1_pool_kernel<<<dim3(2, 8, BATCH), 256, 0, stream>>>(x, c1w, c1b, pool1);
  conv2_pool_kernel<<<dim3(2, 4, BATCH), 256, 0, stream>>>(pool1, c2w, c2b, act);
  fc1_splitk_kernel<<<NPART, 256, 0, stream>>>(act, f1w, part);
  fc1_reduce1_kernel<<<dim3(240, 8), 64, 0, stream>>>(part, part2);
  fc1_reduce2_kernel<<<240, 64, 0, stream>>>(part2, f1b, h1);
  head_kernel<<<BATCH, 128, 0, stream>>>(h1, f2w, f2b, f3w, f3b, sup, out);
}